// Round 7
// baseline (274.162 us; speedup 1.0000x reference)
//
#include <hip/hip_runtime.h>
#include <stdint.h>

// NCA: B=8, C=16, H=W=128, hidden=128, 8 steps.
// ws: [0,8MB) midA | [8,16MB) midB | +512KB mid3cA | +512KB mid3cB |
//     +128KB preA | +128KB preB | +40KB f16 weights. ~17.3 MB.
// mask_kernel is GONE: each step wave regenerates its own 16 mask words
// (8 threefry/lane) inside the load-latency stall. fmaskzero stays fused
// (kill at tap-consume); H stays register-resident.

#define BATCH 8
#define CH 16
#define HT 128
#define WD 128
#define HIDN 128
#define PLANE (HT*WD)
#define IMG (CH*PLANE)
#define NELEM (BATCH*IMG)
#define NPIX (BATCH*PLANE)
#define NSTEPS 8

// ---- step kernel LDS (per wave; intra-wave only -> zero barriers) ----
//   P (perceived f16 hi/lo): 16 rows x 72 halves x 2B = 2304 B each
//   kcm / kfl: 3 x 36 fp32 = 432 B each;  kmw: 16 mask words = 64 B
#define PSTR 72      // 144B rows: 16B-aligned b128 frag reads, spread banks
#define PLO_OFF 2304
#define KCM_OFF 4608
#define KF_OFF  5056
#define KMW_OFF 5488
#define WREG    5552 // x4 waves = 22208 B/block

typedef _Float16 f16x8 __attribute__((ext_vector_type(8)));
typedef _Float16 f16x4 __attribute__((ext_vector_type(4)));
typedef float    f32x4 __attribute__((ext_vector_type(4)));

struct Keys { unsigned k[2*NSTEPS]; };

__host__ __device__ __forceinline__ unsigned rotl32u(unsigned v, int r) {
  return (v << r) | (v >> (32 - r));
}

// JAX threefry2x32 (20 rounds).
__host__ __device__ __forceinline__ void tf2x32(unsigned k0, unsigned k1,
                                                unsigned c0, unsigned c1,
                                                unsigned &o0, unsigned &o1) {
  const unsigned ks2 = k0 ^ k1 ^ 0x1BD11BDAu;
  unsigned x0 = c0 + k0, x1 = c1 + k1;
  x0 += x1; x1 = rotl32u(x1, 13); x1 ^= x0;
  x0 += x1; x1 = rotl32u(x1, 15); x1 ^= x0;
  x0 += x1; x1 = rotl32u(x1, 26); x1 ^= x0;
  x0 += x1; x1 = rotl32u(x1,  6); x1 ^= x0;
  x0 += k1; x1 += ks2 + 1u;
  x0 += x1; x1 = rotl32u(x1, 17); x1 ^= x0;
  x0 += x1; x1 = rotl32u(x1, 29); x1 ^= x0;
  x0 += x1; x1 = rotl32u(x1, 16); x1 ^= x0;
  x0 += x1; x1 = rotl32u(x1, 24); x1 ^= x0;
  x0 += ks2; x1 += k0 + 2u;
  x0 += x1; x1 = rotl32u(x1, 13); x1 ^= x0;
  x0 += x1; x1 = rotl32u(x1, 15); x1 ^= x0;
  x0 += x1; x1 = rotl32u(x1, 26); x1 ^= x0;
  x0 += x1; x1 = rotl32u(x1,  6); x1 ^= x0;
  x0 += k0; x1 += k1 + 3u;
  x0 += x1; x1 = rotl32u(x1, 17); x1 ^= x0;
  x0 += x1; x1 = rotl32u(x1, 29); x1 ^= x0;
  x0 += x1; x1 = rotl32u(x1, 16); x1 ^= x0;
  x0 += x1; x1 = rotl32u(x1, 24); x1 ^= x0;
  x0 += k1; x1 += ks2 + 4u;
  x0 += x1; x1 = rotl32u(x1, 13); x1 ^= x0;
  x0 += x1; x1 = rotl32u(x1, 15); x1 ^= x0;
  x0 += x1; x1 = rotl32u(x1, 26); x1 ^= x0;
  x0 += x1; x1 = rotl32u(x1,  6); x1 ^= x0;
  x0 += ks2; x1 += k0 + 5u;
  o0 = x0; o1 = x1;
}

// f16 hi/lo split weights pre-packed in MFMA fragment order.
// w1f (A-frag of swapped GEMM1): [kt(2)][nt(8)][lane(64)][i(8)],
//   k = kt*32+(lane>>4)*8+i (k>=48 zero), hidden = nt*16+(lane&15).
// w2f (A-frag of swapped GEMM2, sigma-permuted k-slots):
//   [kt(4)][lane(64)][i(8)], k = kt*32 + (i<4 ? 4*g+i : 16+4*g+(i-4)),
//   g=(lane>>4)&3, o = lane&15.
__global__ __launch_bounds__(256) void wpack_kernel(
    const float* __restrict__ w1, const float* __restrict__ w2,
    _Float16* __restrict__ w1fh, _Float16* __restrict__ w1fl,
    _Float16* __restrict__ w2fh, _Float16* __restrict__ w2fl) {
  int t = blockIdx.x * 256 + threadIdx.x;   // 10240 threads
  if (t < 8192) {
    int lane = (t >> 3) & 63, i = t & 7;
    int kt = t >> 12, nt = (t >> 9) & 7;
    int k = kt * 32 + (lane >> 4) * 8 + i;
    int n = nt * 16 + (lane & 15);
    float v = (k < 48) ? w1[n * 48 + k] : 0.f;
    _Float16 h = (_Float16)v;
    w1fh[t] = h;
    w1fl[t] = (_Float16)(v - (float)h);
  } else {
    int u = t - 8192;                        // 2048 threads
    int lane = (u >> 3) & 63, i = u & 7;
    int kt = u >> 9;
    int g = (lane >> 4) & 3;
    int o = lane & 15;
    int kk = (i < 4) ? (4 * g + i) : (16 + 4 * g + (i - 4));
    float v = w2[o * HIDN + kt * 32 + kk];
    _Float16 h = (_Float16)v;
    w2fh[u] = h;
    w2fl[u] = (_Float16)(v - (float)h);
  }
}

// MFMA step kernel. Each wave owns 32 consecutive-x pixels (2 tiles).
// Phase order engineered for latency hiding: (1) issue ALL 72 tap loads +
// kill loads, (2) threefry mask regen (pure VALU, fills the load stall),
// (3) kill-table assembly, (4) consume taps -> P -> GEMM1 -> H(reg) ->
// GEMM2 -> epilogue. Zero barriers (intra-wave LDS only).
__global__ __launch_bounds__(256, 3) void step_mfma(
    const float* __restrict__ s,
    const f16x8* __restrict__ w1fh, const f16x8* __restrict__ w1fl,
    const f16x8* __restrict__ w2fh, const f16x8* __restrict__ w2fl,
    const float* __restrict__ bias1, const float* __restrict__ bias2,
    float* __restrict__ mid,
    const float* __restrict__ mid3cR,   // prev step's ch3 snapshot
    float* __restrict__ mid3cW,         // this step's ch3 snapshot
    const unsigned char* __restrict__ preR,  // prev step's pre bits
    unsigned char* __restrict__ preW,        // this step's pre bits
    const unsigned k0s, const unsigned k1s,  // this step's threefry key
    const int hasKill) {
  __shared__ __align__(16) char smem[4 * WREG];
  const int tid = threadIdx.x;
  const int wv = tid >> 6;
  const int l  = tid & 63;
  const int p  = l & 15;        // MFMA row/col lane index
  const int g  = l >> 4;        // lane group (k-group for frags)
  char* wb = smem + wv * WREG;
  _Float16* Phi = (_Float16*)wb;
  _Float16* Plo = (_Float16*)(wb + PLO_OFF);
  float*    kcm = (float*)(wb + KCM_OFF);   // [3][36] col-max of 3 rows
  float*    kfl = (float*)(wb + KF_OFF);    // [3][36] kill factors
  unsigned* kmw = (unsigned*)(wb + KMW_OFF);// [16] mask words

  const int pid0 = blockIdx.x * 128 + wv * 32;  // wave's first pixel
  const int b  = pid0 >> 14;
  const int r0 = pid0 & 16383;
  const int y  = r0 >> 7;
  const int x0 = r0 & 127;                      // = wv*32
  const bool yu = (y > 0), yd = (y < HT - 1);

  // ---- phase 1a: issue ALL 72 perceive tap loads (both tiles) ----
  const float* sb = s + b * IMG;
  float tap[2][4][9];
  #pragma unroll
  for (int t = 0; t < 2; ++t) {
    const int xt = x0 + 16 * t + p;
    const int ctr = y * WD + xt;
    const bool xl = (xt > 0), xr = (xt < WD - 1);
    #pragma unroll
    for (int cc = 0; cc < 4; ++cc) {
      const float* sc = sb + (g * 4 + cc) * PLANE + ctr;
      tap[t][cc][4] = sc[0];
      tap[t][cc][0] = (yu && xl) ? sc[-WD - 1] : 0.f;
      tap[t][cc][1] = yu         ? sc[-WD]     : 0.f;
      tap[t][cc][2] = (yu && xr) ? sc[-WD + 1] : 0.f;
      tap[t][cc][3] = xl         ? sc[-1]      : 0.f;
      tap[t][cc][5] = xr         ? sc[1]       : 0.f;
      tap[t][cc][6] = (yd && xl) ? sc[WD - 1]  : 0.f;
      tap[t][cc][7] = yd         ? sc[WD]      : 0.f;
      tap[t][cc][8] = (yd && xr) ? sc[WD + 1]  : 0.f;
    }
  }

  // ---- phase 1b: issue kill-table loads + colmax (few, consumed later) ----
  if (hasKill) {
    const float* m3 = mid3cR + b * PLANE;
    #pragma unroll
    for (int rr = 0; rr < 2; ++rr) {
      const int e = l + rr * 64;
      if (e < 108) {
        const int kr = e / 36;            // output row y-1+kr
        const int kc = e - kr * 36;       // col x0-2+kc
        const int xx = x0 - 2 + kc;
        float cm = -1e30f;
        if ((unsigned)xx < WD) {
          #pragma unroll
          for (int dr = -1; dr <= 1; ++dr) {
            const int ry = y - 1 + kr + dr;
            if ((unsigned)ry < HT) cm = fmaxf(cm, m3[ry * WD + xx]);
          }
        }
        kcm[kr * 36 + kc] = cm;
      }
    }
  }

  // ---- phase 2: fused mask regen (pure VALU; fills the load stall) ----
  // lane quad (c16 = l>>2, q = l&3): byte q of word for channel c16.
  // Bit formula identical to the old mask_kernel -> identical bits.
  {
    const int c16 = l >> 2;
    const int q   = l & 3;
    const unsigned widx = (((unsigned)(b * CH + c16) * HT + (unsigned)y) << 2)
                          + (unsigned)(x0 >> 5);
    const unsigned ebase = (widx << 5) + (unsigned)(q * 8);
    unsigned byte = 0u;
    #pragma unroll
    for (int j = 0; j < 8; ++j) {
      unsigned o0, o1;
      tf2x32(k0s, k1s, 0u, ebase + (unsigned)j, o0, o1);
      unsigned bits = o0 ^ o1;
      byte |= (((bits >> 9) != 0u) ? 1u : 0u) << j;
    }
    unsigned part = byte << (q * 8);
    part |= (unsigned)__shfl_xor((int)part, 1);
    part |= (unsigned)__shfl_xor((int)part, 2);
    if (q == 0) kmw[c16] = part;
  }

  // ---- phase 3: kill-factor assembly (kcm -> kfl) ----
  if (hasKill) {
    asm volatile("" ::: "memory");  // kcm writes before kcm reads
    const unsigned char* prb = preR + b * PLANE;
    #pragma unroll
    for (int rr = 0; rr < 2; ++rr) {
      const int e = l + rr * 64;
      if (e < 102) {
        const int kr = e / 34;
        const int kc = e - kr * 34;
        const int yy = y - 1 + kr;
        const int xx = x0 - 1 + kc;
        float kf = 0.f;
        if ((unsigned)yy < HT && (unsigned)xx < WD) {
          const float* c0 = kcm + kr * 36 + kc;
          float mx = fmaxf(fmaxf(c0[0], c0[1]), c0[2]);
          kf = ((mx > 0.1f) && prb[yy * WD + xx]) ? 1.f : 0.f;
        }
        kfl[kr * 36 + kc] = kf;
      }
    }
  } else {
    #pragma unroll
    for (int rr = 0; rr < 2; ++rr) {
      const int e = l + rr * 64;
      if (e < 108) kfl[e] = 1.f;          // [3][36] all-alive
    }
  }

  // Early broadcast loads + P zero-pad (feats 48..63, 16 rows x {hi,lo}).
  const float4 b2q = *(const float4*)(bias2 + g * 4);
  {
    uint4 z; z.x = 0u; z.y = 0u; z.z = 0u; z.w = 0u;
    _Float16* zb = (l & 32) ? Plo : Phi;
    *(uint4*)(zb + (l & 15) * PSTR + 48 + ((l >> 4) & 1) * 8) = z;
  }

  asm volatile("" ::: "memory");  // kill/pad/mask-word writes before reads

  unsigned mw[4];
  #pragma unroll
  for (int cc = 0; cc < 4; ++cc) mw[cc] = kmw[g * 4 + cc];

  // ---- phase 4: consume taps -> P, tile-sequenced through SAME P region ----
  float sctr[2][4];
  float premax[2] = {-1e30f, -1e30f};
  f16x8 pbh[2][2], pbl[2][2];   // P B-fragments (hi/lo, kt=0/1) per tile
  #pragma unroll
  for (int t = 0; t < 2; ++t) {
    float kf9[9];
    {
      const int kc = 16 * t + p;
      #pragma unroll
      for (int dy2 = 0; dy2 < 3; ++dy2)
        #pragma unroll
        for (int dx2 = 0; dx2 < 3; ++dx2)
          kf9[dy2 * 3 + dx2] = kfl[dy2 * 36 + kc + dx2];
    }
    f16x4 vh0, vh1, vh2, vl0, vl1, vl2;
    #pragma unroll
    for (int cc = 0; cc < 4; ++cc) {
      float a11 = tap[t][cc][4] * kf9[4];
      float a00 = tap[t][cc][0] * kf9[0];
      float a01 = tap[t][cc][1] * kf9[1];
      float a02 = tap[t][cc][2] * kf9[2];
      float a10 = tap[t][cc][3] * kf9[3];
      float a12 = tap[t][cc][5] * kf9[5];
      float a20 = tap[t][cc][6] * kf9[6];
      float a21 = tap[t][cc][7] * kf9[7];
      float a22 = tap[t][cc][8] * kf9[8];
      float sx = (a02 - a00) + 2.f * (a12 - a10) + (a22 - a20);
      float sy = (a20 - a00) + 2.f * (a21 - a01) + (a22 - a02);
      sctr[t][cc] = a11;
      _Float16 h0 = (_Float16)a11;
      _Float16 h1 = (_Float16)sx;
      _Float16 h2 = (_Float16)sy;
      vh0[cc] = h0; vl0[cc] = (_Float16)(a11 - (float)h0);
      vh1[cc] = h1; vl1[cc] = (_Float16)(sx - (float)h1);
      vh2[cc] = h2; vl2[cc] = (_Float16)(sy - (float)h2);
      if (g == 0 && cc == 3) {   // alive channel: pre-update maxpool (killed)
        float m0 = fmaxf(fmaxf(a00, a01), fmaxf(a02, a10));
        float m1 = fmaxf(fmaxf(a11, a12), fmaxf(a20, a21));
        premax[t] = fmaxf(fmaxf(m0, m1), a22);
      }
    }
    *(f16x4*)(Phi + p * PSTR + 4 * g)      = vh0;
    *(f16x4*)(Phi + p * PSTR + 16 + 4 * g) = vh1;
    *(f16x4*)(Phi + p * PSTR + 32 + 4 * g) = vh2;
    *(f16x4*)(Plo + p * PSTR + 4 * g)      = vl0;
    *(f16x4*)(Plo + p * PSTR + 16 + 4 * g) = vl1;
    *(f16x4*)(Plo + p * PSTR + 32 + 4 * g) = vl2;
    asm volatile("" ::: "memory");  // P writes before B-frag reads
    const _Float16* prow = Phi + p * PSTR;
    const _Float16* lrow = Plo + p * PSTR;
    pbh[t][0] = *(const f16x8*)(prow + g * 8);
    pbh[t][1] = *(const f16x8*)(prow + 32 + g * 8);
    pbl[t][0] = *(const f16x8*)(lrow + g * 8);
    pbl[t][1] = *(const f16x8*)(lrow + 32 + g * 8);
    asm volatile("" ::: "memory");  // B-frag reads before tile1 P writes
  }

  // ---- GEMM1 (swapped): acc[t][nt] = bias1 + W1 x P, split-f16.
  // D1[row=hidden nt*16+g*4+q][col=pixel p]: lane holds ITS pixel's hiddens.
  f32x4 acc[2][8];
  #pragma unroll
  for (int nt = 0; nt < 8; ++nt) {
    const float4 bq = *(const float4*)(bias1 + nt * 16 + 4 * g);
    f32x4 v = {bq.x, bq.y, bq.z, bq.w};
    acc[0][nt] = v;
    acc[1][nt] = v;
  }
  #pragma unroll
  for (int nt = 0; nt < 8; ++nt) {
    f16x8 w1h0 = w1fh[nt * 64 + l];
    f16x8 w1h1 = w1fh[512 + nt * 64 + l];
    f16x8 w1l0 = w1fl[nt * 64 + l];
    f16x8 w1l1 = w1fl[512 + nt * 64 + l];
    #pragma unroll
    for (int t = 0; t < 2; ++t) {
      acc[t][nt] = __builtin_amdgcn_mfma_f32_16x16x32_f16(w1h0, pbh[t][0], acc[t][nt], 0, 0, 0);
      acc[t][nt] = __builtin_amdgcn_mfma_f32_16x16x32_f16(w1h1, pbh[t][1], acc[t][nt], 0, 0, 0);
      acc[t][nt] = __builtin_amdgcn_mfma_f32_16x16x32_f16(w1l0, pbh[t][0], acc[t][nt], 0, 0, 0);
      acc[t][nt] = __builtin_amdgcn_mfma_f32_16x16x32_f16(w1l1, pbh[t][1], acc[t][nt], 0, 0, 0);
      acc[t][nt] = __builtin_amdgcn_mfma_f32_16x16x32_f16(w1h0, pbl[t][0], acc[t][nt], 0, 0, 0);
      acc[t][nt] = __builtin_amdgcn_mfma_f32_16x16x32_f16(w1h1, pbl[t][1], acc[t][nt], 0, 0, 0);
    }
  }

  // GEMM2 W2 A-fragments (sigma-packed; shared by both tiles).
  f16x8 w2h[4], w2l[4];
  #pragma unroll
  for (int kt = 0; kt < 4; ++kt) {
    w2h[kt] = w2fh[kt * 64 + l];
    w2l[kt] = w2fl[kt * 64 + l];
  }

  // ---- H in registers + GEMM2 per tile ----
  // B-frag slot i of kt holds hidden kt*32 + sigma(g,i):
  //   i<4 -> acc[2kt][i]; i>=4 -> acc[2kt+1][i-4].
  f32x4 dxr[2];
  #pragma unroll
  for (int t = 0; t < 2; ++t) {
    f16x8 hB[4], lB[4];
    #pragma unroll
    for (int kt = 0; kt < 4; ++kt) {
      #pragma unroll
      for (int i2 = 0; i2 < 4; ++i2) {
        float h0 = fmaxf(acc[t][2 * kt][i2], 0.f);
        _Float16 hh0 = (_Float16)h0;
        hB[kt][i2] = hh0;
        lB[kt][i2] = (_Float16)(h0 - (float)hh0);
        float h1 = fmaxf(acc[t][2 * kt + 1][i2], 0.f);
        _Float16 hh1 = (_Float16)h1;
        hB[kt][4 + i2] = hh1;
        lB[kt][4 + i2] = (_Float16)(h1 - (float)hh1);
      }
    }
    f32x4 accP = {b2q.x, b2q.y, b2q.z, b2q.w};
    f32x4 accQ = {0.f, 0.f, 0.f, 0.f};
    f32x4 accR = {0.f, 0.f, 0.f, 0.f};
    #pragma unroll
    for (int kt = 0; kt < 4; ++kt) {
      accP = __builtin_amdgcn_mfma_f32_16x16x32_f16(w2h[kt], hB[kt], accP, 0, 0, 0);
      accQ = __builtin_amdgcn_mfma_f32_16x16x32_f16(w2l[kt], hB[kt], accQ, 0, 0, 0);
      accR = __builtin_amdgcn_mfma_f32_16x16x32_f16(w2h[kt], lB[kt], accR, 0, 0, 0);
    }
    dxr[t] = (accP + accQ) + accR;
  }

  if (g == 0) {
    preW[pid0 + p]      = (premax[0] > 0.1f) ? 1 : 0;
    preW[pid0 + 16 + p] = (premax[1] > 0.1f) ? 1 : 0;
  }

  // ---- epilogue: lane -> (pixel 16t+p, channels 4g..4g+3). mid stays
  // UNMASKED (next step / step_b applies the kill). Coalesced stores.
  #pragma unroll
  for (int t = 0; t < 2; ++t) {
    const int xt = x0 + 16 * t + p;
    const int rt = y * WD + xt;
    #pragma unroll
    for (int cc = 0; cc < 4; ++cc) {
      const int c = g * 4 + cc;
      float d = dxr[t][cc];
      d = fminf(fmaxf(d, -5.f), 5.f);
      float v = sctr[t][cc] + (((mw[cc] >> (16 * t + p)) & 1u) ? d : 0.f);
      mid[b * IMG + c * PLANE + rt] = v;
      if (g == 0 && cc == 3) mid3cW[pid0 + 16 * t + p] = v;  // ch3 snapshot
    }
  }
}

// UNCHANGED: final post-alive maxpool + apply pre&post (reads RAW mid).
__global__ __launch_bounds__(256) void step_b(
    const float* __restrict__ mid,
    const unsigned char* __restrict__ pre,
    float* __restrict__ out) {
  int t = blockIdx.x * 256 + threadIdx.x;   // NPIX threads
  int cq = t >> 15;
  int qid = t & 32767;
  int b = qid >> 12;
  int r = qid & 4095;
  int y = r >> 5;
  int x0 = (r & 31) * 4;
  const float* m3 = mid + b * IMG + 3 * PLANE;

  float col[6];
  #pragma unroll
  for (int j = 0; j < 6; ++j) {
    int xx = x0 - 1 + j;
    float m = -1e30f;
    if ((unsigned)xx < WD) {
      #pragma unroll
      for (int dy = -1; dy <= 1; ++dy) {
        int yy = y + dy;
        if ((unsigned)yy < HT) m = fmaxf(m, m3[yy * WD + xx]);
      }
    }
    col[j] = m;
  }

  const unsigned char* pr = pre + b * PLANE + y * WD + x0;
  float f[4];
  #pragma unroll
  for (int i = 0; i < 4; ++i) {
    float mx = fmaxf(fmaxf(col[i], col[i + 1]), col[i + 2]);
    f[i] = ((mx > 0.1f) && pr[i]) ? 1.f : 0.f;
  }

  #pragma unroll
  for (int cc = 0; cc < 4; ++cc) {
    int c = cq * 4 + cc;
    const float4 v = *(const float4*)&mid[b * IMG + c * PLANE + y * WD + x0];
    float4 w;
    w.x = v.x * f[0]; w.y = v.y * f[1]; w.z = v.z * f[2]; w.w = v.w * f[3];
    *(float4*)&out[b * IMG + c * PLANE + y * WD + x0] = w;
  }
}

extern "C" void kernel_launch(void* const* d_in, const int* in_sizes, int n_in,
                              void* d_out, int out_size, void* d_ws, size_t ws_size,
                              hipStream_t stream) {
  const float* x  = (const float*)d_in[0];
  const float* w1 = (const float*)d_in[1];
  const float* b1 = (const float*)d_in[2];
  const float* w2 = (const float*)d_in[3];
  const float* b2 = (const float*)d_in[4];
  float* out = (float*)d_out;

  char* ws = (char*)d_ws;
  float* midbuf[2];
  midbuf[0] = (float*)ws;
  midbuf[1] = (float*)(ws + (size_t)NELEM * 4);
  float* m3b[2];
  m3b[0] = (float*)(ws + 2 * (size_t)NELEM * 4);
  m3b[1] = m3b[0] + NPIX;
  unsigned char* preb[2];
  preb[0] = (unsigned char*)(ws + 2 * (size_t)NELEM * 4 + 2 * (size_t)NPIX * 4);
  preb[1] = preb[0] + NPIX;
  _Float16* w1fh = (_Float16*)(ws + 2 * (size_t)NELEM * 4
                               + 2 * (size_t)NPIX * 4 + 2 * (size_t)NPIX);
  _Float16* w1fl = w1fh + 8192;
  _Float16* w2fh = w1fl + 8192;
  _Float16* w2fl = w2fh + 2048;

  // keys = jax.random.split(key(42), 8): keys[j] = threefry2x32((0,42),(0,j))
  Keys keys;
  for (int j = 0; j < NSTEPS; ++j) {
    unsigned a, b;
    tf2x32(0u, 42u, 0u, (unsigned)j, a, b);
    keys.k[2 * j] = a; keys.k[2 * j + 1] = b;
  }

  wpack_kernel<<<40, 256, 0, stream>>>(w1, w2, w1fh, w1fl, w2fh, w2fl);

  for (int s = 0; s < NSTEPS; ++s) {
    const float* src = (s == 0) ? x : midbuf[(s - 1) & 1];
    const int cur = s & 1, prv = cur ^ 1;
    step_mfma<<<NPIX / 128, 256, 0, stream>>>(
        src,
        (const f16x8*)w1fh, (const f16x8*)w1fl,
        (const f16x8*)w2fh, (const f16x8*)w2fl,
        b1, b2,
        midbuf[cur],
        m3b[prv], m3b[cur],     // read prev snapshot, write own
        preb[prv], preb[cur],   // read prev pre bits, write own
        keys.k[2 * s], keys.k[2 * s + 1],
        (s > 0) ? 1 : 0);
  }
  step_b<<<NPIX / 256, 256, 0, stream>>>(
      midbuf[(NSTEPS - 1) & 1], preb[(NSTEPS - 1) & 1], out);
}

// Round 10
// 246.984 us; speedup vs baseline: 1.1100x; 1.1100x over previous
//
#include <hip/hip_runtime.h>
#include <stdint.h>

// NCA: B=8, C=16, H=W=128, hidden=128, 8 steps.
// ws: [0,8MB) midA | [8,16MB) midB | +512KB mid3cA | +512KB mid3cB |
//     +128KB preA | +128KB preB | +2MB mask | +40KB f16 weights. ~19.3 MB.
// Exact round-6 step math (proven 266.8us, absmax 0.03125). Round 10 delta:
// mask generation moves OFF the critical path into co-scheduled tail blocks
// of the step launch (step s's launch generates step s+1's mask words in
// 256 extra blocks; step 0's mask rides on the wpack launch). Bitwise the
// same mask words; step kernel math untouched. waves_per_eu reverted
// (r8/r9: correlated with corruption under both fence types).

#define BATCH 8
#define CH 16
#define HT 128
#define WD 128
#define HIDN 128
#define PLANE (HT*WD)
#define IMG (CH*PLANE)
#define NELEM (BATCH*IMG)
#define NPIX (BATCH*PLANE)
#define WORDS_PER_STEP (NELEM/32)
#define NSTEPS 8
#define STEP_BLOCKS (NPIX/128)          // 1024
#define MASK_BLOCKS (WORDS_PER_STEP/256) // 256

// ---- step kernel LDS (per wave; intra-wave only -> zero barriers) ----
//   P (perceived f16 hi/lo): 16 rows x 72 halves x 2B = 2304 B each
//   kcm / kfl: 3 x 36 fp32 = 432 B each
#define PSTR 72      // 144B rows: 16B-aligned b128 frag reads, spread banks
#define PLO_OFF 2304
#define KCM_OFF 4608
#define KF_OFF  5056
#define WREG    5504 // x4 waves = 22016 B/block

#define MEM_FENCE() asm volatile("" ::: "memory")

typedef _Float16 f16x8 __attribute__((ext_vector_type(8)));
typedef _Float16 f16x4 __attribute__((ext_vector_type(4)));
typedef float    f32x4 __attribute__((ext_vector_type(4)));

struct Keys { unsigned k[2*NSTEPS]; };

__host__ __device__ __forceinline__ unsigned rotl32u(unsigned v, int r) {
  return (v << r) | (v >> (32 - r));
}

// JAX threefry2x32 (20 rounds).
__host__ __device__ __forceinline__ void tf2x32(unsigned k0, unsigned k1,
                                                unsigned c0, unsigned c1,
                                                unsigned &o0, unsigned &o1) {
  const unsigned ks2 = k0 ^ k1 ^ 0x1BD11BDAu;
  unsigned x0 = c0 + k0, x1 = c1 + k1;
  x0 += x1; x1 = rotl32u(x1, 13); x1 ^= x0;
  x0 += x1; x1 = rotl32u(x1, 15); x1 ^= x0;
  x0 += x1; x1 = rotl32u(x1, 26); x1 ^= x0;
  x0 += x1; x1 = rotl32u(x1,  6); x1 ^= x0;
  x0 += k1; x1 += ks2 + 1u;
  x0 += x1; x1 = rotl32u(x1, 17); x1 ^= x0;
  x0 += x1; x1 = rotl32u(x1, 29); x1 ^= x0;
  x0 += x1; x1 = rotl32u(x1, 16); x1 ^= x0;
  x0 += x1; x1 = rotl32u(x1, 24); x1 ^= x0;
  x0 += ks2; x1 += k0 + 2u;
  x0 += x1; x1 = rotl32u(x1, 13); x1 ^= x0;
  x0 += x1; x1 = rotl32u(x1, 15); x1 ^= x0;
  x0 += x1; x1 = rotl32u(x1, 26); x1 ^= x0;
  x0 += x1; x1 = rotl32u(x1,  6); x1 ^= x0;
  x0 += k0; x1 += k1 + 3u;
  x0 += x1; x1 = rotl32u(x1, 17); x1 ^= x0;
  x0 += x1; x1 = rotl32u(x1, 29); x1 ^= x0;
  x0 += x1; x1 = rotl32u(x1, 16); x1 ^= x0;
  x0 += x1; x1 = rotl32u(x1, 24); x1 ^= x0;
  x0 += k1; x1 += ks2 + 4u;
  x0 += x1; x1 = rotl32u(x1, 13); x1 ^= x0;
  x0 += x1; x1 = rotl32u(x1, 15); x1 ^= x0;
  x0 += x1; x1 = rotl32u(x1, 26); x1 ^= x0;
  x0 += x1; x1 = rotl32u(x1,  6); x1 ^= x0;
  x0 += ks2; x1 += k0 + 5u;
  o0 = x0; o1 = x1;
}

// One mask word, bit-identical to the baseline mask_kernel's formula.
__device__ __forceinline__ unsigned mask_word(unsigned k0, unsigned k1,
                                              unsigned wid) {
  const unsigned base = wid << 5;
  unsigned word = 0u;
  #pragma unroll 4
  for (int i = 0; i < 32; ++i) {
    unsigned b1x, b2x;
    tf2x32(k0, k1, 0u, base + (unsigned)i, b1x, b2x);
    unsigned bits = b1x ^ b2x;
    word |= (((bits >> 9) != 0u) ? 1u : 0u) << i;
  }
  return word;
}

// wpack + step-0 mask in one launch. Blocks [0,40): weight packing
// (unchanged layout); blocks [40,40+256): step-0 mask words.
// w1f (A-frag of swapped GEMM1): [kt(2)][nt(8)][lane(64)][i(8)],
//   k = kt*32+(lane>>4)*8+i (k>=48 zero), hidden = nt*16+(lane&15).
// w2f (A-frag of swapped GEMM2, sigma-permuted k-slots):
//   [kt(4)][lane(64)][i(8)], k = kt*32 + (i<4 ? 4*g+i : 16+4*g+(i-4)),
//   g=(lane>>4)&3, o = lane&15.
__global__ __launch_bounds__(256) void wpack_kernel(
    const float* __restrict__ w1, const float* __restrict__ w2,
    _Float16* __restrict__ w1fh, _Float16* __restrict__ w1fl,
    _Float16* __restrict__ w2fh, _Float16* __restrict__ w2fl,
    unsigned* __restrict__ mask0, unsigned mk0, unsigned mk1) {
  if (blockIdx.x >= 40) {
    const unsigned wid = (blockIdx.x - 40) * 256u + threadIdx.x; // < 65536
    mask0[wid] = mask_word(mk0, mk1, wid);
    return;
  }
  int t = blockIdx.x * 256 + threadIdx.x;   // 10240 threads
  if (t < 8192) {
    int lane = (t >> 3) & 63, i = t & 7;
    int kt = t >> 12, nt = (t >> 9) & 7;
    int k = kt * 32 + (lane >> 4) * 8 + i;
    int n = nt * 16 + (lane & 15);
    float v = (k < 48) ? w1[n * 48 + k] : 0.f;
    _Float16 h = (_Float16)v;
    w1fh[t] = h;
    w1fl[t] = (_Float16)(v - (float)h);
  } else {
    int u = t - 8192;                        // 2048 threads
    int lane = (u >> 3) & 63, i = u & 7;
    int kt = u >> 9;
    int g = (lane >> 4) & 3;
    int o = lane & 15;
    int kk = (i < 4) ? (4 * g + i) : (16 + 4 * g + (i - 4));
    float v = w2[o * HIDN + kt * 32 + kk];
    _Float16 h = (_Float16)v;
    w2fh[u] = h;
    w2fl[u] = (_Float16)(v - (float)h);
  }
}

// MFMA step kernel — EXACT round-6 math. Blocks [0,1024): step work.
// Blocks [1024,1024+256) (present when s<7): generate NEXT step's mask
// words (independent VALU work co-scheduled into this launch's idle issue
// capacity; reads nothing the step blocks write).
__global__ __launch_bounds__(256, 3) void step_mfma(
    const float* __restrict__ s,
    const f16x8* __restrict__ w1fh, const f16x8* __restrict__ w1fl,
    const f16x8* __restrict__ w2fh, const f16x8* __restrict__ w2fl,
    const float* __restrict__ bias1, const float* __restrict__ bias2,
    const unsigned* __restrict__ mask,   // this step's words (read)
    unsigned* __restrict__ maskN,        // next step's words (tail writes)
    const unsigned kn0, const unsigned kn1,  // next step's threefry key
    float* __restrict__ mid,
    const float* __restrict__ mid3cR,   // prev step's ch3 snapshot
    float* __restrict__ mid3cW,         // this step's ch3 snapshot
    const unsigned char* __restrict__ preR,  // prev step's pre bits
    unsigned char* __restrict__ preW,        // this step's pre bits
    const int hasKill) {
  if (blockIdx.x >= STEP_BLOCKS) {     // mask-gen tail block
    const unsigned wid = (blockIdx.x - STEP_BLOCKS) * 256u + threadIdx.x;
    maskN[wid] = mask_word(kn0, kn1, wid);
    return;
  }

  __shared__ __align__(16) char smem[4 * WREG];
  const int tid = threadIdx.x;
  const int wv = tid >> 6;
  const int l  = tid & 63;
  const int p  = l & 15;        // MFMA row/col lane index
  const int g  = l >> 4;        // lane group (k-group for frags)
  char* wb = smem + wv * WREG;
  _Float16* Phi = (_Float16*)wb;
  _Float16* Plo = (_Float16*)(wb + PLO_OFF);
  float*    kcm = (float*)(wb + KCM_OFF);   // [3][36] col-max of 3 rows
  float*    kfl = (float*)(wb + KF_OFF);    // [3][36] kill factors

  const int pid0 = blockIdx.x * 128 + wv * 32;  // wave's first pixel
  const int b  = pid0 >> 14;
  const int r0 = pid0 & 16383;
  const int y  = r0 >> 7;
  const int x0 = r0 & 127;                      // = wv*32
  const bool yu = (y > 0), yd = (y < HT - 1);

  // ---- kill table via colmax: kcm[kr][kc] = max over 3 rows of col ----
  if (hasKill) {
    const float* m3 = mid3cR + b * PLANE;
    #pragma unroll
    for (int rr = 0; rr < 2; ++rr) {
      const int e = l + rr * 64;
      if (e < 108) {
        const int kr = e / 36;            // output row y-1+kr
        const int kc = e - kr * 36;       // col x0-2+kc
        const int xx = x0 - 2 + kc;
        float cm = -1e30f;
        if ((unsigned)xx < WD) {
          #pragma unroll
          for (int dr = -1; dr <= 1; ++dr) {
            const int ry = y - 1 + kr + dr;
            if ((unsigned)ry < HT) cm = fmaxf(cm, m3[ry * WD + xx]);
          }
        }
        kcm[kr * 36 + kc] = cm;
      }
    }
    MEM_FENCE();  // kcm writes before kcm reads
    const unsigned char* prb = preR + b * PLANE;
    #pragma unroll
    for (int rr = 0; rr < 2; ++rr) {
      const int e = l + rr * 64;
      if (e < 102) {
        const int kr = e / 34;
        const int kc = e - kr * 34;
        const int yy = y - 1 + kr;
        const int xx = x0 - 1 + kc;
        float kf = 0.f;
        if ((unsigned)yy < HT && (unsigned)xx < WD) {
          const float* c0 = kcm + kr * 36 + kc;
          float mx = fmaxf(fmaxf(c0[0], c0[1]), c0[2]);
          kf = ((mx > 0.1f) && prb[yy * WD + xx]) ? 1.f : 0.f;
        }
        kfl[kr * 36 + kc] = kf;
      }
    }
  } else {
    #pragma unroll
    for (int rr = 0; rr < 2; ++rr) {
      const int e = l + rr * 64;
      if (e < 108) kfl[e] = 1.f;          // [3][36] all-alive
    }
  }

  // Early independent loads (overlap with perceive).
  const float4 b2q = *(const float4*)(bias2 + g * 4);
  unsigned mw[4];
  #pragma unroll
  for (int cc = 0; cc < 4; ++cc)
    mw[cc] = mask[((b * CH + g * 4 + cc) * HT + y) * (WD / 32) + (x0 >> 5)];

  // Zero-pad P feats 48..63 (16 rows x {hi,lo}): one 16B chunk per lane.
  {
    uint4 z; z.x = 0u; z.y = 0u; z.z = 0u; z.w = 0u;
    _Float16* zb = (l & 32) ? Plo : Phi;
    *(uint4*)(zb + (l & 15) * PSTR + 48 + ((l >> 4) & 1) * 8) = z;
  }

  MEM_FENCE();  // kill-table/pad writes before reads

  // ---- perceive both tiles, tile-sequenced through the SAME P region ----
  const float* sb = s + b * IMG;
  float sctr[2][4];
  float premax[2] = {-1e30f, -1e30f};
  f16x8 pbh[2][2], pbl[2][2];   // P B-fragments (hi/lo, kt=0/1) per tile
  #pragma unroll
  for (int t = 0; t < 2; ++t) {
    const int xt = x0 + 16 * t + p;
    const int ctr = y * WD + xt;
    const bool xl = (xt > 0), xr = (xt < WD - 1);
    float kf9[9];
    {
      const int kc = 16 * t + p;
      #pragma unroll
      for (int dy2 = 0; dy2 < 3; ++dy2)
        #pragma unroll
        for (int dx2 = 0; dx2 < 3; ++dx2)
          kf9[dy2 * 3 + dx2] = kfl[dy2 * 36 + kc + dx2];
    }
    f16x4 vh0, vh1, vh2, vl0, vl1, vl2;
    #pragma unroll
    for (int cc = 0; cc < 4; ++cc) {
      const int c = g * 4 + cc;
      const float* sc = sb + c * PLANE + ctr;
      float a11 = sc[0] * kf9[4];
      float a00 = ((yu && xl) ? sc[-WD - 1] : 0.f) * kf9[0];
      float a01 = (yu         ? sc[-WD]     : 0.f) * kf9[1];
      float a02 = ((yu && xr) ? sc[-WD + 1] : 0.f) * kf9[2];
      float a10 = (xl         ? sc[-1]      : 0.f) * kf9[3];
      float a12 = (xr         ? sc[1]       : 0.f) * kf9[5];
      float a20 = ((yd && xl) ? sc[WD - 1]  : 0.f) * kf9[6];
      float a21 = (yd         ? sc[WD]      : 0.f) * kf9[7];
      float a22 = ((yd && xr) ? sc[WD + 1]  : 0.f) * kf9[8];
      float sx = (a02 - a00) + 2.f * (a12 - a10) + (a22 - a20);
      float sy = (a20 - a00) + 2.f * (a21 - a01) + (a22 - a02);
      sctr[t][cc] = a11;
      _Float16 h0 = (_Float16)a11;
      _Float16 h1 = (_Float16)sx;
      _Float16 h2 = (_Float16)sy;
      vh0[cc] = h0; vl0[cc] = (_Float16)(a11 - (float)h0);
      vh1[cc] = h1; vl1[cc] = (_Float16)(sx - (float)h1);
      vh2[cc] = h2; vl2[cc] = (_Float16)(sy - (float)h2);
      if (g == 0 && cc == 3) {   // alive channel: pre-update maxpool (killed)
        float m0 = fmaxf(fmaxf(a00, a01), fmaxf(a02, a10));
        float m1 = fmaxf(fmaxf(a11, a12), fmaxf(a20, a21));
        premax[t] = fmaxf(fmaxf(m0, m1), a22);
      }
    }
    *(f16x4*)(Phi + p * PSTR + 4 * g)      = vh0;
    *(f16x4*)(Phi + p * PSTR + 16 + 4 * g) = vh1;
    *(f16x4*)(Phi + p * PSTR + 32 + 4 * g) = vh2;
    *(f16x4*)(Plo + p * PSTR + 4 * g)      = vl0;
    *(f16x4*)(Plo + p * PSTR + 16 + 4 * g) = vl1;
    *(f16x4*)(Plo + p * PSTR + 32 + 4 * g) = vl2;
    MEM_FENCE();  // P writes before B-frag reads
    const _Float16* prow = Phi + p * PSTR;
    const _Float16* lrow = Plo + p * PSTR;
    pbh[t][0] = *(const f16x8*)(prow + g * 8);
    pbh[t][1] = *(const f16x8*)(prow + 32 + g * 8);
    pbl[t][0] = *(const f16x8*)(lrow + g * 8);
    pbl[t][1] = *(const f16x8*)(lrow + 32 + g * 8);
    MEM_FENCE();  // B-frag reads before tile1 P writes
  }

  // ---- GEMM1 (swapped): acc[t][nt] = bias1 + W1 x P, split-f16.
  // D1[row=hidden nt*16+g*4+q][col=pixel p]: lane holds ITS pixel's hiddens.
  f32x4 acc[2][8];
  #pragma unroll
  for (int nt = 0; nt < 8; ++nt) {
    const float4 bq = *(const float4*)(bias1 + nt * 16 + 4 * g);
    f32x4 v = {bq.x, bq.y, bq.z, bq.w};
    acc[0][nt] = v;
    acc[1][nt] = v;
  }
  #pragma unroll
  for (int nt = 0; nt < 8; ++nt) {
    f16x8 w1h0 = w1fh[nt * 64 + l];
    f16x8 w1h1 = w1fh[512 + nt * 64 + l];
    f16x8 w1l0 = w1fl[nt * 64 + l];
    f16x8 w1l1 = w1fl[512 + nt * 64 + l];
    #pragma unroll
    for (int t = 0; t < 2; ++t) {
      acc[t][nt] = __builtin_amdgcn_mfma_f32_16x16x32_f16(w1h0, pbh[t][0], acc[t][nt], 0, 0, 0);
      acc[t][nt] = __builtin_amdgcn_mfma_f32_16x16x32_f16(w1h1, pbh[t][1], acc[t][nt], 0, 0, 0);
      acc[t][nt] = __builtin_amdgcn_mfma_f32_16x16x32_f16(w1l0, pbh[t][0], acc[t][nt], 0, 0, 0);
      acc[t][nt] = __builtin_amdgcn_mfma_f32_16x16x32_f16(w1l1, pbh[t][1], acc[t][nt], 0, 0, 0);
      acc[t][nt] = __builtin_amdgcn_mfma_f32_16x16x32_f16(w1h0, pbl[t][0], acc[t][nt], 0, 0, 0);
      acc[t][nt] = __builtin_amdgcn_mfma_f32_16x16x32_f16(w1h1, pbl[t][1], acc[t][nt], 0, 0, 0);
    }
  }

  // GEMM2 W2 A-fragments (sigma-packed; shared by both tiles).
  f16x8 w2h[4], w2l[4];
  #pragma unroll
  for (int kt = 0; kt < 4; ++kt) {
    w2h[kt] = w2fh[kt * 64 + l];
    w2l[kt] = w2fl[kt * 64 + l];
  }

  // ---- H in registers + GEMM2 per tile ----
  // B-frag slot i of kt holds hidden kt*32 + sigma(g,i):
  //   i<4 -> acc[2kt][i]; i>=4 -> acc[2kt+1][i-4].
  f32x4 dxr[2];
  #pragma unroll
  for (int t = 0; t < 2; ++t) {
    f16x8 hB[4], lB[4];
    #pragma unroll
    for (int kt = 0; kt < 4; ++kt) {
      #pragma unroll
      for (int i2 = 0; i2 < 4; ++i2) {
        float h0 = fmaxf(acc[t][2 * kt][i2], 0.f);
        _Float16 hh0 = (_Float16)h0;
        hB[kt][i2] = hh0;
        lB[kt][i2] = (_Float16)(h0 - (float)hh0);
        float h1 = fmaxf(acc[t][2 * kt + 1][i2], 0.f);
        _Float16 hh1 = (_Float16)h1;
        hB[kt][4 + i2] = hh1;
        lB[kt][4 + i2] = (_Float16)(h1 - (float)hh1);
      }
    }
    f32x4 accP = {b2q.x, b2q.y, b2q.z, b2q.w};
    f32x4 accQ = {0.f, 0.f, 0.f, 0.f};
    f32x4 accR = {0.f, 0.f, 0.f, 0.f};
    #pragma unroll
    for (int kt = 0; kt < 4; ++kt) {
      accP = __builtin_amdgcn_mfma_f32_16x16x32_f16(w2h[kt], hB[kt], accP, 0, 0, 0);
      accQ = __builtin_amdgcn_mfma_f32_16x16x32_f16(w2l[kt], hB[kt], accQ, 0, 0, 0);
      accR = __builtin_amdgcn_mfma_f32_16x16x32_f16(w2h[kt], lB[kt], accR, 0, 0, 0);
    }
    dxr[t] = (accP + accQ) + accR;
  }

  if (g == 0) {
    preW[pid0 + p]      = (premax[0] > 0.1f) ? 1 : 0;
    preW[pid0 + 16 + p] = (premax[1] > 0.1f) ? 1 : 0;
  }

  // ---- epilogue: lane -> (pixel 16t+p, channels 4g..4g+3). mid stays
  // UNMASKED (next step / step_b applies the kill). Coalesced stores.
  #pragma unroll
  for (int t = 0; t < 2; ++t) {
    const int xt = x0 + 16 * t + p;
    const int rt = y * WD + xt;
    #pragma unroll
    for (int cc = 0; cc < 4; ++cc) {
      const int c = g * 4 + cc;
      float d = dxr[t][cc];
      d = fminf(fmaxf(d, -5.f), 5.f);
      float v = sctr[t][cc] + (((mw[cc] >> (16 * t + p)) & 1u) ? d : 0.f);
      mid[b * IMG + c * PLANE + rt] = v;
      if (g == 0 && cc == 3) mid3cW[pid0 + 16 * t + p] = v;  // ch3 snapshot
    }
  }
}

// UNCHANGED: final post-alive maxpool + apply pre&post (reads RAW mid).
__global__ __launch_bounds__(256) void step_b(
    const float* __restrict__ mid,
    const unsigned char* __restrict__ pre,
    float* __restrict__ out) {
  int t = blockIdx.x * 256 + threadIdx.x;   // NPIX threads
  int cq = t >> 15;
  int qid = t & 32767;
  int b = qid >> 12;
  int r = qid & 4095;
  int y = r >> 5;
  int x0 = (r & 31) * 4;
  const float* m3 = mid + b * IMG + 3 * PLANE;

  float col[6];
  #pragma unroll
  for (int j = 0; j < 6; ++j) {
    int xx = x0 - 1 + j;
    float m = -1e30f;
    if ((unsigned)xx < WD) {
      #pragma unroll
      for (int dy = -1; dy <= 1; ++dy) {
        int yy = y + dy;
        if ((unsigned)yy < HT) m = fmaxf(m, m3[yy * WD + xx]);
      }
    }
    col[j] = m;
  }

  const unsigned char* pr = pre + b * PLANE + y * WD + x0;
  float f[4];
  #pragma unroll
  for (int i = 0; i < 4; ++i) {
    float mx = fmaxf(fmaxf(col[i], col[i + 1]), col[i + 2]);
    f[i] = ((mx > 0.1f) && pr[i]) ? 1.f : 0.f;
  }

  #pragma unroll
  for (int cc = 0; cc < 4; ++cc) {
    int c = cq * 4 + cc;
    const float4 v = *(const float4*)&mid[b * IMG + c * PLANE + y * WD + x0];
    float4 w;
    w.x = v.x * f[0]; w.y = v.y * f[1]; w.z = v.z * f[2]; w.w = v.w * f[3];
    *(float4*)&out[b * IMG + c * PLANE + y * WD + x0] = w;
  }
}

extern "C" void kernel_launch(void* const* d_in, const int* in_sizes, int n_in,
                              void* d_out, int out_size, void* d_ws, size_t ws_size,
                              hipStream_t stream) {
  const float* x  = (const float*)d_in[0];
  const float* w1 = (const float*)d_in[1];
  const float* b1 = (const float*)d_in[2];
  const float* w2 = (const float*)d_in[3];
  const float* b2 = (const float*)d_in[4];
  float* out = (float*)d_out;

  char* ws = (char*)d_ws;
  float* midbuf[2];
  midbuf[0] = (float*)ws;
  midbuf[1] = (float*)(ws + (size_t)NELEM * 4);
  float* m3b[2];
  m3b[0] = (float*)(ws + 2 * (size_t)NELEM * 4);
  m3b[1] = m3b[0] + NPIX;
  unsigned char* preb[2];
  preb[0] = (unsigned char*)(ws + 2 * (size_t)NELEM * 4 + 2 * (size_t)NPIX * 4);
  preb[1] = preb[0] + NPIX;
  unsigned* mask = (unsigned*)(ws + 2 * (size_t)NELEM * 4
                                  + 2 * (size_t)NPIX * 4 + 2 * (size_t)NPIX);
  _Float16* w1fh = (_Float16*)((char*)mask
                               + (size_t)NSTEPS * WORDS_PER_STEP * 4);
  _Float16* w1fl = w1fh + 8192;
  _Float16* w2fh = w1fl + 8192;
  _Float16* w2fl = w2fh + 2048;

  // keys = jax.random.split(key(42), 8): keys[j] = threefry2x32((0,42),(0,j))
  Keys keys;
  for (int j = 0; j < NSTEPS; ++j) {
    unsigned a, b;
    tf2x32(0u, 42u, 0u, (unsigned)j, a, b);
    keys.k[2 * j] = a; keys.k[2 * j + 1] = b;
  }

  // wpack + step-0 mask in one launch (40 weight blocks + 256 mask blocks).
  wpack_kernel<<<40 + MASK_BLOCKS, 256, 0, stream>>>(
      w1, w2, w1fh, w1fl, w2fh, w2fl, mask, keys.k[0], keys.k[1]);

  for (int s = 0; s < NSTEPS; ++s) {
    const float* src = (s == 0) ? x : midbuf[(s - 1) & 1];
    const int cur = s & 1, prv = cur ^ 1;
    const bool genNext = (s + 1 < NSTEPS);
    step_mfma<<<STEP_BLOCKS + (genNext ? MASK_BLOCKS : 0), 256, 0, stream>>>(
        src,
        (const f16x8*)w1fh, (const f16x8*)w1fl,
        (const f16x8*)w2fh, (const f16x8*)w2fl,
        b1, b2,
        mask + s * WORDS_PER_STEP,
        mask + (genNext ? (s + 1) : s) * WORDS_PER_STEP,  // tail writes (unused when s=7)
        keys.k[2 * (genNext ? (s + 1) : s)],
        keys.k[2 * (genNext ? (s + 1) : s) + 1],
        midbuf[cur],
        m3b[prv], m3b[cur],     // read prev snapshot, write own
        preb[prv], preb[cur],   // read prev pre bits, write own
        (s > 0) ? 1 : 0);
  }
  step_b<<<NPIX / 256, 256, 0, stream>>>(
      midbuf[(NSTEPS - 1) & 1], preb[(NSTEPS - 1) & 1], out);
}

// Round 11
// 220.915 us; speedup vs baseline: 1.2410x; 1.1180x over previous
//
#include <hip/hip_runtime.h>
#include <stdint.h>

// NCA: B=8, C=16, H=W=128, hidden=128, 8 steps.
// ws: [0,8MB) midA | [8,16MB) midB | +512KB mid3cA | +512KB mid3cB |
//     +128KB preA | +128KB preB | +2MB mask | +40KB f16 weights. ~19.3 MB.
// Round-6 step math (proven bit-exact), round-10 co-scheduled mask tails.
// Round 11 delta: XCD-residency block swizzle — b = blockIdx&7, y = blk>>3,
// so with round-robin blockIdx%8->XCD dispatch each XCD owns ONE batch
// image (~2.6MB working set < 4MB XCD L2) across all 8 steps: halo reads
// become local-L2 hits instead of cross-XCD L3 trips. Pure permutation of
// block->row assignment -> bitwise-identical output.

#define BATCH 8
#define CH 16
#define HT 128
#define WD 128
#define HIDN 128
#define PLANE (HT*WD)
#define IMG (CH*PLANE)
#define NELEM (BATCH*IMG)
#define NPIX (BATCH*PLANE)
#define WORDS_PER_STEP (NELEM/32)
#define NSTEPS 8
#define STEP_BLOCKS (NPIX/128)          // 1024 = 8 XCDs x 128 rows
#define MASK_BLOCKS (WORDS_PER_STEP/256) // 256

// ---- step kernel LDS (per wave; intra-wave only -> zero barriers) ----
//   P (perceived f16 hi/lo): 16 rows x 72 halves x 2B = 2304 B each
//   kcm / kfl: 3 x 36 fp32 = 432 B each
#define PSTR 72      // 144B rows: 16B-aligned b128 frag reads, spread banks
#define PLO_OFF 2304
#define KCM_OFF 4608
#define KF_OFF  5056
#define WREG    5504 // x4 waves = 22016 B/block

#define MEM_FENCE() asm volatile("" ::: "memory")

typedef _Float16 f16x8 __attribute__((ext_vector_type(8)));
typedef _Float16 f16x4 __attribute__((ext_vector_type(4)));
typedef float    f32x4 __attribute__((ext_vector_type(4)));

struct Keys { unsigned k[2*NSTEPS]; };

__host__ __device__ __forceinline__ unsigned rotl32u(unsigned v, int r) {
  return (v << r) | (v >> (32 - r));
}

// JAX threefry2x32 (20 rounds).
__host__ __device__ __forceinline__ void tf2x32(unsigned k0, unsigned k1,
                                                unsigned c0, unsigned c1,
                                                unsigned &o0, unsigned &o1) {
  const unsigned ks2 = k0 ^ k1 ^ 0x1BD11BDAu;
  unsigned x0 = c0 + k0, x1 = c1 + k1;
  x0 += x1; x1 = rotl32u(x1, 13); x1 ^= x0;
  x0 += x1; x1 = rotl32u(x1, 15); x1 ^= x0;
  x0 += x1; x1 = rotl32u(x1, 26); x1 ^= x0;
  x0 += x1; x1 = rotl32u(x1,  6); x1 ^= x0;
  x0 += k1; x1 += ks2 + 1u;
  x0 += x1; x1 = rotl32u(x1, 17); x1 ^= x0;
  x0 += x1; x1 = rotl32u(x1, 29); x1 ^= x0;
  x0 += x1; x1 = rotl32u(x1, 16); x1 ^= x0;
  x0 += x1; x1 = rotl32u(x1, 24); x1 ^= x0;
  x0 += ks2; x1 += k0 + 2u;
  x0 += x1; x1 = rotl32u(x1, 13); x1 ^= x0;
  x0 += x1; x1 = rotl32u(x1, 15); x1 ^= x0;
  x0 += x1; x1 = rotl32u(x1, 26); x1 ^= x0;
  x0 += x1; x1 = rotl32u(x1,  6); x1 ^= x0;
  x0 += k0; x1 += k1 + 3u;
  x0 += x1; x1 = rotl32u(x1, 17); x1 ^= x0;
  x0 += x1; x1 = rotl32u(x1, 29); x1 ^= x0;
  x0 += x1; x1 = rotl32u(x1, 16); x1 ^= x0;
  x0 += x1; x1 = rotl32u(x1, 24); x1 ^= x0;
  x0 += k1; x1 += ks2 + 4u;
  x0 += x1; x1 = rotl32u(x1, 13); x1 ^= x0;
  x0 += x1; x1 = rotl32u(x1, 15); x1 ^= x0;
  x0 += x1; x1 = rotl32u(x1, 26); x1 ^= x0;
  x0 += x1; x1 = rotl32u(x1,  6); x1 ^= x0;
  x0 += ks2; x1 += k0 + 5u;
  o0 = x0; o1 = x1;
}

// One mask word, bit-identical to the baseline mask_kernel's formula.
__device__ __forceinline__ unsigned mask_word(unsigned k0, unsigned k1,
                                              unsigned wid) {
  const unsigned base = wid << 5;
  unsigned word = 0u;
  #pragma unroll 4
  for (int i = 0; i < 32; ++i) {
    unsigned b1x, b2x;
    tf2x32(k0, k1, 0u, base + (unsigned)i, b1x, b2x);
    unsigned bits = b1x ^ b2x;
    word |= (((bits >> 9) != 0u) ? 1u : 0u) << i;
  }
  return word;
}

// wpack + step-0 mask in one launch. Blocks [0,40): weight packing;
// blocks [40,40+256): step-0 mask words.
// w1f (A-frag of swapped GEMM1): [kt(2)][nt(8)][lane(64)][i(8)],
//   k = kt*32+(lane>>4)*8+i (k>=48 zero), hidden = nt*16+(lane&15).
// w2f (A-frag of swapped GEMM2, sigma-permuted k-slots):
//   [kt(4)][lane(64)][i(8)], k = kt*32 + (i<4 ? 4*g+i : 16+4*g+(i-4)),
//   g=(lane>>4)&3, o = lane&15.
__global__ __launch_bounds__(256) void wpack_kernel(
    const float* __restrict__ w1, const float* __restrict__ w2,
    _Float16* __restrict__ w1fh, _Float16* __restrict__ w1fl,
    _Float16* __restrict__ w2fh, _Float16* __restrict__ w2fl,
    unsigned* __restrict__ mask0, unsigned mk0, unsigned mk1) {
  if (blockIdx.x >= 40) {
    const unsigned wid = (blockIdx.x - 40) * 256u + threadIdx.x; // < 65536
    mask0[wid] = mask_word(mk0, mk1, wid);
    return;
  }
  int t = blockIdx.x * 256 + threadIdx.x;   // 10240 threads
  if (t < 8192) {
    int lane = (t >> 3) & 63, i = t & 7;
    int kt = t >> 12, nt = (t >> 9) & 7;
    int k = kt * 32 + (lane >> 4) * 8 + i;
    int n = nt * 16 + (lane & 15);
    float v = (k < 48) ? w1[n * 48 + k] : 0.f;
    _Float16 h = (_Float16)v;
    w1fh[t] = h;
    w1fl[t] = (_Float16)(v - (float)h);
  } else {
    int u = t - 8192;                        // 2048 threads
    int lane = (u >> 3) & 63, i = u & 7;
    int kt = u >> 9;
    int g = (lane >> 4) & 3;
    int o = lane & 15;
    int kk = (i < 4) ? (4 * g + i) : (16 + 4 * g + (i - 4));
    float v = w2[o * HIDN + kt * 32 + kk];
    _Float16 h = (_Float16)v;
    w2fh[u] = h;
    w2fl[u] = (_Float16)(v - (float)h);
  }
}

// MFMA step kernel — round-6 math, XCD-residency block mapping.
// Blocks [0,1024): step work, b = blk&7 (XCD-resident image), y = blk>>3.
// Blocks [1024,1024+256) (when s<7): generate NEXT step's mask words.
__global__ __launch_bounds__(256, 3) void step_mfma(
    const float* __restrict__ s,
    const f16x8* __restrict__ w1fh, const f16x8* __restrict__ w1fl,
    const f16x8* __restrict__ w2fh, const f16x8* __restrict__ w2fl,
    const float* __restrict__ bias1, const float* __restrict__ bias2,
    const unsigned* __restrict__ mask,   // this step's words (read)
    unsigned* __restrict__ maskN,        // next step's words (tail writes)
    const unsigned kn0, const unsigned kn1,  // next step's threefry key
    float* __restrict__ mid,
    const float* __restrict__ mid3cR,   // prev step's ch3 snapshot
    float* __restrict__ mid3cW,         // this step's ch3 snapshot
    const unsigned char* __restrict__ preR,  // prev step's pre bits
    unsigned char* __restrict__ preW,        // this step's pre bits
    const int hasKill) {
  if (blockIdx.x >= STEP_BLOCKS) {     // mask-gen tail block
    const unsigned wid = (blockIdx.x - STEP_BLOCKS) * 256u + threadIdx.x;
    maskN[wid] = mask_word(kn0, kn1, wid);
    return;
  }

  __shared__ __align__(16) char smem[4 * WREG];
  const int tid = threadIdx.x;
  const int wv = tid >> 6;
  const int l  = tid & 63;
  const int p  = l & 15;        // MFMA row/col lane index
  const int g  = l >> 4;        // lane group (k-group for frags)
  char* wb = smem + wv * WREG;
  _Float16* Phi = (_Float16*)wb;
  _Float16* Plo = (_Float16*)(wb + PLO_OFF);
  float*    kcm = (float*)(wb + KCM_OFF);   // [3][36] col-max of 3 rows
  float*    kfl = (float*)(wb + KF_OFF);    // [3][36] kill factors

  // XCD-residency mapping: image b lives on XCD (blockIdx%8) every step.
  const int b  = (int)(blockIdx.x & 7);
  const int y  = (int)(blockIdx.x >> 3);
  const int x0 = wv * 32;
  const int pid0 = ((b << 7) + y) * 128 + x0;   // wave's first pixel
  const bool yu = (y > 0), yd = (y < HT - 1);

  // ---- kill table via colmax: kcm[kr][kc] = max over 3 rows of col ----
  if (hasKill) {
    const float* m3 = mid3cR + b * PLANE;
    #pragma unroll
    for (int rr = 0; rr < 2; ++rr) {
      const int e = l + rr * 64;
      if (e < 108) {
        const int kr = e / 36;            // output row y-1+kr
        const int kc = e - kr * 36;       // col x0-2+kc
        const int xx = x0 - 2 + kc;
        float cm = -1e30f;
        if ((unsigned)xx < WD) {
          #pragma unroll
          for (int dr = -1; dr <= 1; ++dr) {
            const int ry = y - 1 + kr + dr;
            if ((unsigned)ry < HT) cm = fmaxf(cm, m3[ry * WD + xx]);
          }
        }
        kcm[kr * 36 + kc] = cm;
      }
    }
    MEM_FENCE();  // kcm writes before kcm reads
    const unsigned char* prb = preR + b * PLANE;
    #pragma unroll
    for (int rr = 0; rr < 2; ++rr) {
      const int e = l + rr * 64;
      if (e < 102) {
        const int kr = e / 34;
        const int kc = e - kr * 34;
        const int yy = y - 1 + kr;
        const int xx = x0 - 1 + kc;
        float kf = 0.f;
        if ((unsigned)yy < HT && (unsigned)xx < WD) {
          const float* c0 = kcm + kr * 36 + kc;
          float mx = fmaxf(fmaxf(c0[0], c0[1]), c0[2]);
          kf = ((mx > 0.1f) && prb[yy * WD + xx]) ? 1.f : 0.f;
        }
        kfl[kr * 36 + kc] = kf;
      }
    }
  } else {
    #pragma unroll
    for (int rr = 0; rr < 2; ++rr) {
      const int e = l + rr * 64;
      if (e < 108) kfl[e] = 1.f;          // [3][36] all-alive
    }
  }

  // Early independent loads (overlap with perceive).
  const float4 b2q = *(const float4*)(bias2 + g * 4);
  unsigned mw[4];
  #pragma unroll
  for (int cc = 0; cc < 4; ++cc)
    mw[cc] = mask[((b * CH + g * 4 + cc) * HT + y) * (WD / 32) + (x0 >> 5)];

  // Zero-pad P feats 48..63 (16 rows x {hi,lo}): one 16B chunk per lane.
  {
    uint4 z; z.x = 0u; z.y = 0u; z.z = 0u; z.w = 0u;
    _Float16* zb = (l & 32) ? Plo : Phi;
    *(uint4*)(zb + (l & 15) * PSTR + 48 + ((l >> 4) & 1) * 8) = z;
  }

  MEM_FENCE();  // kill-table/pad writes before reads

  // ---- perceive both tiles, tile-sequenced through the SAME P region ----
  const float* sb = s + b * IMG;
  float sctr[2][4];
  float premax[2] = {-1e30f, -1e30f};
  f16x8 pbh[2][2], pbl[2][2];   // P B-fragments (hi/lo, kt=0/1) per tile
  #pragma unroll
  for (int t = 0; t < 2; ++t) {
    const int xt = x0 + 16 * t + p;
    const int ctr = y * WD + xt;
    const bool xl = (xt > 0), xr = (xt < WD - 1);
    float kf9[9];
    {
      const int kc = 16 * t + p;
      #pragma unroll
      for (int dy2 = 0; dy2 < 3; ++dy2)
        #pragma unroll
        for (int dx2 = 0; dx2 < 3; ++dx2)
          kf9[dy2 * 3 + dx2] = kfl[dy2 * 36 + kc + dx2];
    }
    f16x4 vh0, vh1, vh2, vl0, vl1, vl2;
    #pragma unroll
    for (int cc = 0; cc < 4; ++cc) {
      const int c = g * 4 + cc;
      const float* sc = sb + c * PLANE + ctr;
      float a11 = sc[0] * kf9[4];
      float a00 = ((yu && xl) ? sc[-WD - 1] : 0.f) * kf9[0];
      float a01 = (yu         ? sc[-WD]     : 0.f) * kf9[1];
      float a02 = ((yu && xr) ? sc[-WD + 1] : 0.f) * kf9[2];
      float a10 = (xl         ? sc[-1]      : 0.f) * kf9[3];
      float a12 = (xr         ? sc[1]       : 0.f) * kf9[5];
      float a20 = ((yd && xl) ? sc[WD - 1]  : 0.f) * kf9[6];
      float a21 = (yd         ? sc[WD]      : 0.f) * kf9[7];
      float a22 = ((yd && xr) ? sc[WD + 1]  : 0.f) * kf9[8];
      float sx = (a02 - a00) + 2.f * (a12 - a10) + (a22 - a20);
      float sy = (a20 - a00) + 2.f * (a21 - a01) + (a22 - a02);
      sctr[t][cc] = a11;
      _Float16 h0 = (_Float16)a11;
      _Float16 h1 = (_Float16)sx;
      _Float16 h2 = (_Float16)sy;
      vh0[cc] = h0; vl0[cc] = (_Float16)(a11 - (float)h0);
      vh1[cc] = h1; vl1[cc] = (_Float16)(sx - (float)h1);
      vh2[cc] = h2; vl2[cc] = (_Float16)(sy - (float)h2);
      if (g == 0 && cc == 3) {   // alive channel: pre-update maxpool (killed)
        float m0 = fmaxf(fmaxf(a00, a01), fmaxf(a02, a10));
        float m1 = fmaxf(fmaxf(a11, a12), fmaxf(a20, a21));
        premax[t] = fmaxf(fmaxf(m0, m1), a22);
      }
    }
    *(f16x4*)(Phi + p * PSTR + 4 * g)      = vh0;
    *(f16x4*)(Phi + p * PSTR + 16 + 4 * g) = vh1;
    *(f16x4*)(Phi + p * PSTR + 32 + 4 * g) = vh2;
    *(f16x4*)(Plo + p * PSTR + 4 * g)      = vl0;
    *(f16x4*)(Plo + p * PSTR + 16 + 4 * g) = vl1;
    *(f16x4*)(Plo + p * PSTR + 32 + 4 * g) = vl2;
    MEM_FENCE();  // P writes before B-frag reads
    const _Float16* prow = Phi + p * PSTR;
    const _Float16* lrow = Plo + p * PSTR;
    pbh[t][0] = *(const f16x8*)(prow + g * 8);
    pbh[t][1] = *(const f16x8*)(prow + 32 + g * 8);
    pbl[t][0] = *(const f16x8*)(lrow + g * 8);
    pbl[t][1] = *(const f16x8*)(lrow + 32 + g * 8);
    MEM_FENCE();  // B-frag reads before tile1 P writes
  }

  // ---- GEMM1 (swapped): acc[t][nt] = bias1 + W1 x P, split-f16.
  // D1[row=hidden nt*16+g*4+q][col=pixel p]: lane holds ITS pixel's hiddens.
  f32x4 acc[2][8];
  #pragma unroll
  for (int nt = 0; nt < 8; ++nt) {
    const float4 bq = *(const float4*)(bias1 + nt * 16 + 4 * g);
    f32x4 v = {bq.x, bq.y, bq.z, bq.w};
    acc[0][nt] = v;
    acc[1][nt] = v;
  }
  #pragma unroll
  for (int nt = 0; nt < 8; ++nt) {
    f16x8 w1h0 = w1fh[nt * 64 + l];
    f16x8 w1h1 = w1fh[512 + nt * 64 + l];
    f16x8 w1l0 = w1fl[nt * 64 + l];
    f16x8 w1l1 = w1fl[512 + nt * 64 + l];
    #pragma unroll
    for (int t = 0; t < 2; ++t) {
      acc[t][nt] = __builtin_amdgcn_mfma_f32_16x16x32_f16(w1h0, pbh[t][0], acc[t][nt], 0, 0, 0);
      acc[t][nt] = __builtin_amdgcn_mfma_f32_16x16x32_f16(w1h1, pbh[t][1], acc[t][nt], 0, 0, 0);
      acc[t][nt] = __builtin_amdgcn_mfma_f32_16x16x32_f16(w1l0, pbh[t][0], acc[t][nt], 0, 0, 0);
      acc[t][nt] = __builtin_amdgcn_mfma_f32_16x16x32_f16(w1l1, pbh[t][1], acc[t][nt], 0, 0, 0);
      acc[t][nt] = __builtin_amdgcn_mfma_f32_16x16x32_f16(w1h0, pbl[t][0], acc[t][nt], 0, 0, 0);
      acc[t][nt] = __builtin_amdgcn_mfma_f32_16x16x32_f16(w1h1, pbl[t][1], acc[t][nt], 0, 0, 0);
    }
  }

  // GEMM2 W2 A-fragments (sigma-packed; shared by both tiles).
  f16x8 w2h[4], w2l[4];
  #pragma unroll
  for (int kt = 0; kt < 4; ++kt) {
    w2h[kt] = w2fh[kt * 64 + l];
    w2l[kt] = w2fl[kt * 64 + l];
  }

  // ---- H in registers + GEMM2 per tile ----
  // B-frag slot i of kt holds hidden kt*32 + sigma(g,i):
  //   i<4 -> acc[2kt][i]; i>=4 -> acc[2kt+1][i-4].
  f32x4 dxr[2];
  #pragma unroll
  for (int t = 0; t < 2; ++t) {
    f16x8 hB[4], lB[4];
    #pragma unroll
    for (int kt = 0; kt < 4; ++kt) {
      #pragma unroll
      for (int i2 = 0; i2 < 4; ++i2) {
        float h0 = fmaxf(acc[t][2 * kt][i2], 0.f);
        _Float16 hh0 = (_Float16)h0;
        hB[kt][i2] = hh0;
        lB[kt][i2] = (_Float16)(h0 - (float)hh0);
        float h1 = fmaxf(acc[t][2 * kt + 1][i2], 0.f);
        _Float16 hh1 = (_Float16)h1;
        hB[kt][4 + i2] = hh1;
        lB[kt][4 + i2] = (_Float16)(h1 - (float)hh1);
      }
    }
    f32x4 accP = {b2q.x, b2q.y, b2q.z, b2q.w};
    f32x4 accQ = {0.f, 0.f, 0.f, 0.f};
    f32x4 accR = {0.f, 0.f, 0.f, 0.f};
    #pragma unroll
    for (int kt = 0; kt < 4; ++kt) {
      accP = __builtin_amdgcn_mfma_f32_16x16x32_f16(w2h[kt], hB[kt], accP, 0, 0, 0);
      accQ = __builtin_amdgcn_mfma_f32_16x16x32_f16(w2l[kt], hB[kt], accQ, 0, 0, 0);
      accR = __builtin_amdgcn_mfma_f32_16x16x32_f16(w2h[kt], lB[kt], accR, 0, 0, 0);
    }
    dxr[t] = (accP + accQ) + accR;
  }

  if (g == 0) {
    preW[pid0 + p]      = (premax[0] > 0.1f) ? 1 : 0;
    preW[pid0 + 16 + p] = (premax[1] > 0.1f) ? 1 : 0;
  }

  // ---- epilogue: lane -> (pixel 16t+p, channels 4g..4g+3). mid stays
  // UNMASKED (next step / step_b applies the kill). Coalesced stores.
  #pragma unroll
  for (int t = 0; t < 2; ++t) {
    const int xt = x0 + 16 * t + p;
    const int rt = y * WD + xt;
    #pragma unroll
    for (int cc = 0; cc < 4; ++cc) {
      const int c = g * 4 + cc;
      float d = dxr[t][cc];
      d = fminf(fmaxf(d, -5.f), 5.f);
      float v = sctr[t][cc] + (((mw[cc] >> (16 * t + p)) & 1u) ? d : 0.f);
      mid[b * IMG + c * PLANE + rt] = v;
      if (g == 0 && cc == 3) mid3cW[pid0 + 16 * t + p] = v;  // ch3 snapshot
    }
  }
}

// Final post-alive maxpool + apply pre&post (reads RAW mid). Same math as
// baseline; block index permuted so batch b's blocks land on XCD b
// (hardware blockIdx%8), reading the L2-resident image.
__global__ __launch_bounds__(256) void step_b(
    const float* __restrict__ mid,
    const unsigned char* __restrict__ pre,
    float* __restrict__ out) {
  const unsigned h = blockIdx.x;            // 512 blocks
  const unsigned j = h >> 3;
  const unsigned kl = ((j >> 4) << 7) | ((h & 7) << 4) | (j & 15);
  int t = (int)kl * 256 + threadIdx.x;      // same (cq,b,r) coverage
  int cq = t >> 15;
  int qid = t & 32767;
  int b = qid >> 12;
  int r = qid & 4095;
  int y = r >> 5;
  int x0 = (r & 31) * 4;
  const float* m3 = mid + b * IMG + 3 * PLANE;

  float col[6];
  #pragma unroll
  for (int j2 = 0; j2 < 6; ++j2) {
    int xx = x0 - 1 + j2;
    float m = -1e30f;
    if ((unsigned)xx < WD) {
      #pragma unroll
      for (int dy = -1; dy <= 1; ++dy) {
        int yy = y + dy;
        if ((unsigned)yy < HT) m = fmaxf(m, m3[yy * WD + xx]);
      }
    }
    col[j2] = m;
  }

  const unsigned char* pr = pre + b * PLANE + y * WD + x0;
  float f[4];
  #pragma unroll
  for (int i = 0; i < 4; ++i) {
    float mx = fmaxf(fmaxf(col[i], col[i + 1]), col[i + 2]);
    f[i] = ((mx > 0.1f) && pr[i]) ? 1.f : 0.f;
  }

  #pragma unroll
  for (int cc = 0; cc < 4; ++cc) {
    int c = cq * 4 + cc;
    const float4 v = *(const float4*)&mid[b * IMG + c * PLANE + y * WD + x0];
    float4 w;
    w.x = v.x * f[0]; w.y = v.y * f[1]; w.z = v.z * f[2]; w.w = v.w * f[3];
    *(float4*)&out[b * IMG + c * PLANE + y * WD + x0] = w;
  }
}

extern "C" void kernel_launch(void* const* d_in, const int* in_sizes, int n_in,
                              void* d_out, int out_size, void* d_ws, size_t ws_size,
                              hipStream_t stream) {
  const float* x  = (const float*)d_in[0];
  const float* w1 = (const float*)d_in[1];
  const float* b1 = (const float*)d_in[2];
  const float* w2 = (const float*)d_in[3];
  const float* b2 = (const float*)d_in[4];
  float* out = (float*)d_out;

  char* ws = (char*)d_ws;
  float* midbuf[2];
  midbuf[0] = (float*)ws;
  midbuf[1] = (float*)(ws + (size_t)NELEM * 4);
  float* m3b[2];
  m3b[0] = (float*)(ws + 2 * (size_t)NELEM * 4);
  m3b[1] = m3b[0] + NPIX;
  unsigned char* preb[2];
  preb[0] = (unsigned char*)(ws + 2 * (size_t)NELEM * 4 + 2 * (size_t)NPIX * 4);
  preb[1] = preb[0] + NPIX;
  unsigned* mask = (unsigned*)(ws + 2 * (size_t)NELEM * 4
                                  + 2 * (size_t)NPIX * 4 + 2 * (size_t)NPIX);
  _Float16* w1fh = (_Float16*)((char*)mask
                               + (size_t)NSTEPS * WORDS_PER_STEP * 4);
  _Float16* w1fl = w1fh + 8192;
  _Float16* w2fh = w1fl + 8192;
  _Float16* w2fl = w2fh + 2048;

  // keys = jax.random.split(key(42), 8): keys[j] = threefry2x32((0,42),(0,j))
  Keys keys;
  for (int j = 0; j < NSTEPS; ++j) {
    unsigned a, b;
    tf2x32(0u, 42u, 0u, (unsigned)j, a, b);
    keys.k[2 * j] = a; keys.k[2 * j + 1] = b;
  }

  // wpack + step-0 mask in one launch (40 weight blocks + 256 mask blocks).
  wpack_kernel<<<40 + MASK_BLOCKS, 256, 0, stream>>>(
      w1, w2, w1fh, w1fl, w2fh, w2fl, mask, keys.k[0], keys.k[1]);

  for (int s = 0; s < NSTEPS; ++s) {
    const float* src = (s == 0) ? x : midbuf[(s - 1) & 1];
    const int cur = s & 1, prv = cur ^ 1;
    const bool genNext = (s + 1 < NSTEPS);
    step_mfma<<<STEP_BLOCKS + (genNext ? MASK_BLOCKS : 0), 256, 0, stream>>>(
        src,
        (const f16x8*)w1fh, (const f16x8*)w1fl,
        (const f16x8*)w2fh, (const f16x8*)w2fl,
        b1, b2,
        mask + s * WORDS_PER_STEP,
        mask + (genNext ? (s + 1) : s) * WORDS_PER_STEP,  // tail writes (unused when s=7)
        keys.k[2 * (genNext ? (s + 1) : s)],
        keys.k[2 * (genNext ? (s + 1) : s) + 1],
        midbuf[cur],
        m3b[prv], m3b[cur],     // read prev snapshot, write own
        preb[prv], preb[cur],   // read prev pre bits, write own
        (s > 0) ? 1 : 0);
  }
  step_b<<<NPIX / 256, 256, 0, stream>>>(
      midbuf[(NSTEPS - 1) & 1], preb[(NSTEPS - 1) & 1], out);
}